// Round 1
// baseline (168.557 us; speedup 1.0000x reference)
//
#include <hip/hip_runtime.h>
#include <math.h>

// Chunked parallel IIR with decay halo.
// alpha = exp(-2*pi*20/44100) ~ 0.997154; alpha^HALO ~ 8.5e-6 -> halo truncation
// error ~1.7e-5, far below the 0.1075 absmax threshold.
#define TPB 256
#define SEG 64                   // elements per thread (kept in registers)
#define HALO 4096                // 64 threads * SEG; must be multiple of SEG
#define BLK (TPB * SEG)          // 16384 elements staged per block
#define CSZ (BLK - HALO)         // 12288 output elements per block

__device__ __forceinline__ float waveshape(float p, int ty) {
    if (ty == 0) {
        // tanh(p) = 1 - 2/(exp(2p)+1); exact saturation at +/-1 for large |p|
        float e2 = __expf(2.0f * p);
        return 1.0f - 2.0f / (e2 + 1.0f);
    } else if (ty == 1) {
        return fminf(fmaxf(p, -1.0f), 1.0f);
    } else if (ty == 2) {
        float r = p + 1.0f;
        float rem = r - 4.0f * floorf(r * 0.25f);   // jnp.remainder(r, 4)
        return fabsf(rem - 2.0f) - 1.0f;
    } else if (ty == 3) {
        return __sinf(p * 1.5707963267948966f);
    } else {
        return p / (1.0f + fabsf(p));
    }
}

__global__ void __launch_bounds__(TPB)
dist_kernel(const float* __restrict__ x,
            const float* __restrict__ drive,
            const float* __restrict__ bias,
            const float* __restrict__ mix,
            const int* __restrict__ type_idx,
            float* __restrict__ out,
            int N, float alpha)
{
    const int row = blockIdx.y;
    const int tid = threadIdx.x;
    const int ty  = *type_idx;   // wave-uniform

    const float g  = exp2f(drive[row] * 7.972672880099267f);  // 10^(2.4*drive)
    const float dc = bias[row] * 2.0f - 1.0f;
    const float mm = mix[row];
    const float om = 1.0f - mm;

    const long long rowBase = (long long)row * (long long)N;
    const float* __restrict__ xr = x + rowBase;
    float* __restrict__ outr = out + rowBase;

    const int outStart = (int)blockIdx.x * CSZ;
    const int j0 = outStart - HALO + tid * SEG;

    // ---- Phase A: load + waveshape + per-thread local carry (zero init) ----
    float d[SEG];
    float e = 0.0f;
    float dprev0;
    {
        int jp = j0 - 1;
        dprev0 = (jp >= 0 && jp < N) ? waveshape((xr[jp] + dc) * g, ty) : 0.0f;
    }
    const bool full = (j0 >= 0) && (j0 + SEG <= N);
    float dprev = dprev0;
    if (full) {
        #pragma unroll
        for (int k = 0; k < SEG; k += 4) {
            float4 xv = *reinterpret_cast<const float4*>(xr + j0 + k);
            float dv;
            dv = waveshape((xv.x + dc) * g, ty); d[k+0] = dv; e = fmaf(alpha, e, dv - dprev); dprev = dv;
            dv = waveshape((xv.y + dc) * g, ty); d[k+1] = dv; e = fmaf(alpha, e, dv - dprev); dprev = dv;
            dv = waveshape((xv.z + dc) * g, ty); d[k+2] = dv; e = fmaf(alpha, e, dv - dprev); dprev = dv;
            dv = waveshape((xv.w + dc) * g, ty); d[k+3] = dv; e = fmaf(alpha, e, dv - dprev); dprev = dv;
        }
    } else {
        #pragma unroll
        for (int k = 0; k < SEG; ++k) {
            int j = j0 + k;
            bool in = (j >= 0) && (j < N);
            float xs = in ? xr[j] : 0.0f;
            float dv = in ? waveshape((xs + dc) * g, ty) : 0.0f;
            d[k] = dv; e = fmaf(alpha, e, dv - dprev); dprev = dv;
        }
    }

    // ---- Phase B: compose per-thread carries: c' = alpha^SEG * c + e ----
    const int lane = tid & 63;
    const int wv   = tid >> 6;
    float aS = alpha;
    #pragma unroll
    for (int i = 0; i < 6; ++i) aS *= aS;    // alpha^64 (= alpha^SEG)

    float ival = e;    // inclusive scan value within wave
    float m = aS;
    #pragma unroll
    for (int off = 1; off < 64; off <<= 1) {
        float up = __shfl_up(ival, off, 64);
        if (lane >= off) ival = fmaf(m, up, ival);
        m *= m;                               // aS^1, aS^2, ... aS^32; ends at aS^64
    }
    const float aW = m;                       // alpha^(SEG*64) = alpha^4096

    __shared__ float wtot[TPB / 64];
    if (lane == 63) wtot[wv] = ival;
    __syncthreads();

    float P = 0.0f;                           // carry into this wave
    for (int w = 0; w < wv; ++w) P = fmaf(aW, P, wtot[w]);

    float iprev = __shfl_up(ival, 1, 64);
    // aS^lane via binary expansion (exact-ish, 6 steps)
    float ap = 1.0f, b = aS;
    #pragma unroll
    for (int i = 0; i < 6; ++i) { if ((lane >> i) & 1) ap *= b; b *= b; }
    const float carry = fmaf(ap, P, (lane > 0) ? iprev : 0.0f);

    // ---- Phase C: replay with true carry, mix, store (output threads only) ----
    if (tid >= HALO / SEG) {
        float y = carry;
        dprev = dprev0;
        if (full) {
            #pragma unroll
            for (int k = 0; k < SEG; k += 4) {
                float4 xv = *reinterpret_cast<const float4*>(xr + j0 + k);
                float4 ov;
                y = fmaf(alpha, y, d[k+0] - dprev); dprev = d[k+0]; ov.x = fmaf(om, xv.x, mm * y);
                y = fmaf(alpha, y, d[k+1] - dprev); dprev = d[k+1]; ov.y = fmaf(om, xv.y, mm * y);
                y = fmaf(alpha, y, d[k+2] - dprev); dprev = d[k+2]; ov.z = fmaf(om, xv.z, mm * y);
                y = fmaf(alpha, y, d[k+3] - dprev); dprev = d[k+3]; ov.w = fmaf(om, xv.w, mm * y);
                *reinterpret_cast<float4*>(outr + j0 + k) = ov;
            }
        } else {
            #pragma unroll
            for (int k = 0; k < SEG; ++k) {
                int j = j0 + k;
                bool in = (j >= 0) && (j < N);
                float xs = in ? xr[j] : 0.0f;
                y = fmaf(alpha, y, d[k] - dprev); dprev = d[k];
                if (in) outr[j] = fmaf(om, xs, mm * y);
            }
        }
    }
}

extern "C" void kernel_launch(void* const* d_in, const int* in_sizes, int n_in,
                              void* d_out, int out_size, void* d_ws, size_t ws_size,
                              hipStream_t stream) {
    const float* x     = (const float*)d_in[0];
    const float* drive = (const float*)d_in[1];
    const float* bias  = (const float*)d_in[2];
    const float* mixp  = (const float*)d_in[3];
    const int*   tyi   = (const int*)d_in[4];
    float* out = (float*)d_out;

    const int B = in_sizes[1];              // drive is (B,1)
    const int N = in_sizes[0] / B;

    const double alpha_d = exp(-2.0 * M_PI * 20.0 / 44100.0);
    const float alpha = (float)alpha_d;

    const int nChunks = (N + CSZ - 1) / CSZ;
    dim3 grid(nChunks, B);
    dist_kernel<<<grid, TPB, 0, stream>>>(x, drive, bias, mixp, tyi, out, N, alpha);
}

// Round 2
// 136.209 us; speedup vs baseline: 1.2375x; 1.2375x over previous
//
#include <hip/hip_runtime.h>
#include <math.h>

// Chunked parallel IIR with decay halo, all state in registers.
// alpha = exp(-2*pi*20/44100) ~ 0.997154; alpha^2048 ~ 2.9e-3, |y|<=2 ->
// halo truncation error ~6e-3, far below the 0.1075 absmax threshold.
// TPB=1024/SEG=16: x[16]+d[16] = 32 VGPRs/thread -> no spills, no x re-read.
#define TPB 1024
#define SEG 16                   // elements per thread (registers)
#define HALO 2048                // 128 threads * SEG
#define BLK (TPB * SEG)          // 16384 elements per block
#define CSZ (BLK - HALO)         // 14336 output elements per block

__device__ __forceinline__ float waveshape(float p, int ty) {
    if (ty == 0) {
        // tanh(p) = 1 - 2/(exp(2p)+1); exact saturation at +/-1 for large |p|
        float e2 = __expf(2.0f * p);
        return 1.0f - 2.0f / (e2 + 1.0f);
    } else if (ty == 1) {
        return fminf(fmaxf(p, -1.0f), 1.0f);
    } else if (ty == 2) {
        float r = p + 1.0f;
        float rem = r - 4.0f * floorf(r * 0.25f);   // jnp.remainder(r, 4)
        return fabsf(rem - 2.0f) - 1.0f;
    } else if (ty == 3) {
        return __sinf(p * 1.5707963267948966f);
    } else {
        return p / (1.0f + fabsf(p));
    }
}

__global__ void __launch_bounds__(TPB, 8)
dist_kernel(const float* __restrict__ x,
            const float* __restrict__ drive,
            const float* __restrict__ bias,
            const float* __restrict__ mix,
            const int* __restrict__ type_idx,
            float* __restrict__ out,
            int N, float alpha)
{
    const int row = blockIdx.y;
    const int tid = threadIdx.x;
    const int ty  = *type_idx;   // wave-uniform

    const float g  = exp2f(drive[row] * 7.972672880099267f);  // 10^(2.4*drive)
    const float dc = bias[row] * 2.0f - 1.0f;
    const float mm = mix[row];
    const float om = 1.0f - mm;

    const long long rowBase = (long long)row * (long long)N;
    const float* __restrict__ xr = x + rowBase;
    float* __restrict__ outr = out + rowBase;

    const int outStart = (int)blockIdx.x * CSZ;
    const int j0 = outStart - HALO + tid * SEG;

    // ---- Phase A: load x into registers, waveshape, local carry (zero init) ----
    float xreg[SEG];
    float d[SEG];
    float e = 0.0f;
    float dprev0;
    {
        int jp = j0 - 1;
        dprev0 = (jp >= 0 && jp < N) ? waveshape((xr[jp] + dc) * g, ty) : 0.0f;
    }
    const bool full = (j0 >= 0) && (j0 + SEG <= N);
    float dprev = dprev0;
    if (full) {
        #pragma unroll
        for (int k = 0; k < SEG; k += 4) {
            float4 xv = *reinterpret_cast<const float4*>(xr + j0 + k);
            xreg[k+0] = xv.x; xreg[k+1] = xv.y; xreg[k+2] = xv.z; xreg[k+3] = xv.w;
        }
        #pragma unroll
        for (int k = 0; k < SEG; ++k) {
            float dv = waveshape((xreg[k] + dc) * g, ty);
            d[k] = dv; e = fmaf(alpha, e, dv - dprev); dprev = dv;
        }
    } else {
        #pragma unroll
        for (int k = 0; k < SEG; ++k) {
            int j = j0 + k;
            bool in = (j >= 0) && (j < N);
            float xs = in ? xr[j] : 0.0f;
            xreg[k] = xs;
            float dv = in ? waveshape((xs + dc) * g, ty) : 0.0f;
            d[k] = dv; e = fmaf(alpha, e, dv - dprev); dprev = dv;
        }
    }

    // ---- Phase B: compose per-thread carries: c' = alpha^SEG * c + e ----
    const int lane = tid & 63;
    const int wv   = tid >> 6;            // 16 waves
    float aS = alpha;
    #pragma unroll
    for (int i = 0; i < 4; ++i) aS *= aS;    // alpha^16 (= alpha^SEG)

    float ival = e;    // inclusive scan within wave
    float m = aS;
    #pragma unroll
    for (int off = 1; off < 64; off <<= 1) {
        float up = __shfl_up(ival, off, 64);
        if (lane >= off) ival = fmaf(m, up, ival);
        m *= m;                               // ends at aS^64
    }
    const float aW = m;                       // alpha^(SEG*64) = alpha^1024

    __shared__ float wtot[TPB / 64];
    if (lane == 63) wtot[wv] = ival;
    __syncthreads();

    float P = 0.0f;                           // carry into this wave
    for (int w = 0; w < wv; ++w) P = fmaf(aW, P, wtot[w]);

    float iprev = __shfl_up(ival, 1, 64);
    float ap = 1.0f, b = aS;                  // aS^lane via binary expansion
    #pragma unroll
    for (int i = 0; i < 6; ++i) { if ((lane >> i) & 1) ap *= b; b *= b; }
    const float carry = fmaf(ap, P, (lane > 0) ? iprev : 0.0f);

    // ---- Phase C: replay with true carry, mix, store (output threads only) ----
    if (tid >= HALO / SEG) {
        float y = carry;
        dprev = dprev0;
        if (full) {
            #pragma unroll
            for (int k = 0; k < SEG; k += 4) {
                float4 ov;
                y = fmaf(alpha, y, d[k+0] - dprev); dprev = d[k+0]; ov.x = fmaf(om, xreg[k+0], mm * y);
                y = fmaf(alpha, y, d[k+1] - dprev); dprev = d[k+1]; ov.y = fmaf(om, xreg[k+1], mm * y);
                y = fmaf(alpha, y, d[k+2] - dprev); dprev = d[k+2]; ov.z = fmaf(om, xreg[k+2], mm * y);
                y = fmaf(alpha, y, d[k+3] - dprev); dprev = d[k+3]; ov.w = fmaf(om, xreg[k+3], mm * y);
                *reinterpret_cast<float4*>(outr + j0 + k) = ov;
            }
        } else {
            #pragma unroll
            for (int k = 0; k < SEG; ++k) {
                int j = j0 + k;
                bool in = (j >= 0) && (j < N);
                y = fmaf(alpha, y, d[k] - dprev); dprev = d[k];
                if (in) outr[j] = fmaf(om, xreg[k], mm * y);
            }
        }
    }
}

extern "C" void kernel_launch(void* const* d_in, const int* in_sizes, int n_in,
                              void* d_out, int out_size, void* d_ws, size_t ws_size,
                              hipStream_t stream) {
    const float* x     = (const float*)d_in[0];
    const float* drive = (const float*)d_in[1];
    const float* bias  = (const float*)d_in[2];
    const float* mixp  = (const float*)d_in[3];
    const int*   tyi   = (const int*)d_in[4];
    float* out = (float*)d_out;

    const int B = in_sizes[1];              // drive is (B,1)
    const int N = in_sizes[0] / B;

    const double alpha_d = exp(-2.0 * M_PI * 20.0 / 44100.0);
    const float alpha = (float)alpha_d;

    const int nChunks = (N + CSZ - 1) / CSZ;
    dim3 grid(nChunks, B);
    dist_kernel<<<grid, TPB, 0, stream>>>(x, drive, bias, mixp, tyi, out, N, alpha);
}

// Round 4
// 129.889 us; speedup vs baseline: 1.2977x; 1.0487x over previous
//
#include <hip/hip_runtime.h>
#include <math.h>

// Chunked parallel IIR, coalesced layout, z-formulation (no neighbor data).
//   z[i] = alpha*z[i-1] + d[i];  y[i] = d[i] - (1-alpha)*z[i-1]
// Each wave owns 1024 contiguous elements; access k is base+k*256+lane*4
// (contiguous 1KB per wave instruction). Each lane owns 4 runs of 4 elements.
// z composes: run summary (regs) -> lane scan (shfl, alpha^4) -> sub-block
// compose (alpha^256) -> wave compose via LDS (alpha^1024).
// Halo: (1-a)*a^2048*|z|<=0.003 << 0.1075 threshold.
#define TPB 1024
#define WAVES (TPB / 64)         // 16
#define PER_WAVE 1024
#define BLK (WAVES * PER_WAVE)   // 16384
#define HALO 2048
#define CSZ (BLK - HALO)         // 14336 output elements per block

__device__ __forceinline__ float waveshape(float p, int ty) {
    if (ty == 0) {
        // tanh(p) = 1 - 2/(exp(2p)+1); exact saturation at +/-1 for large |p|
        float e2 = __expf(2.0f * p);
        return 1.0f - 2.0f / (e2 + 1.0f);
    } else if (ty == 1) {
        return fminf(fmaxf(p, -1.0f), 1.0f);
    } else if (ty == 2) {
        float r = p + 1.0f;
        float rem = r - 4.0f * floorf(r * 0.25f);   // jnp.remainder(r, 4)
        return fabsf(rem - 2.0f) - 1.0f;
    } else if (ty == 3) {
        return __sinf(p * 1.5707963267948966f);
    } else {
        return p / (1.0f + fabsf(p));
    }
}

__global__ void __launch_bounds__(TPB, 8)
dist_kernel(const float* __restrict__ x,
            const float* __restrict__ drive,
            const float* __restrict__ bias,
            const float* __restrict__ mix,
            const int* __restrict__ type_idx,
            float* __restrict__ out,
            int N, float alpha, float beta)
{
    const int row  = blockIdx.y;
    const int tid  = threadIdx.x;
    const int lane = tid & 63;
    const int wv   = tid >> 6;
    const int ty   = *type_idx;   // wave-uniform

    const float g  = exp2f(drive[row] * 7.972672880099267f);  // 10^(2.4*drive)
    const float dc = bias[row] * 2.0f - 1.0f;
    const float mm = mix[row];
    const float om = 1.0f - mm;

    const long long rowBase = (long long)row * (long long)N;
    const float* __restrict__ xr = x + rowBase;
    float* __restrict__ outr = out + rowBase;

    const int outStart = (int)blockIdx.x * CSZ;
    const int wbase = outStart - HALO + wv * PER_WAVE;

    // ---- Phase A: coalesced loads + waveshape; keep only d in regs ----
    float4 d4[4];
    #pragma unroll
    for (int k = 0; k < 4; ++k) {
        const int j = wbase + k * 256 + lane * 4;
        if (j >= 0 && j + 4 <= N) {
            float4 xv = *reinterpret_cast<const float4*>(xr + j);
            d4[k].x = waveshape((xv.x + dc) * g, ty);
            d4[k].y = waveshape((xv.y + dc) * g, ty);
            d4[k].z = waveshape((xv.z + dc) * g, ty);
            d4[k].w = waveshape((xv.w + dc) * g, ty);
        } else {
            float xs; bool in;
            in = (j+0 >= 0) && (j+0 < N); xs = in ? xr[j+0] : 0.0f; d4[k].x = in ? waveshape((xs + dc) * g, ty) : 0.0f;
            in = (j+1 >= 0) && (j+1 < N); xs = in ? xr[j+1] : 0.0f; d4[k].y = in ? waveshape((xs + dc) * g, ty) : 0.0f;
            in = (j+2 >= 0) && (j+2 < N); xs = in ? xr[j+2] : 0.0f; d4[k].z = in ? waveshape((xs + dc) * g, ty) : 0.0f;
            in = (j+3 >= 0) && (j+3 < N); xs = in ? xr[j+3] : 0.0f; d4[k].w = in ? waveshape((xs + dc) * g, ty) : 0.0f;
        }
    }

    // ---- run summaries: z after lane's 4 elements, zero entry ----
    const float a2 = alpha * alpha;
    const float a4 = a2 * a2;
    float iv[4];
    #pragma unroll
    for (int k = 0; k < 4; ++k) {
        float acc = d4[k].x;
        acc = fmaf(alpha, acc, d4[k].y);
        acc = fmaf(alpha, acc, d4[k].z);
        acc = fmaf(alpha, acc, d4[k].w);
        iv[k] = acc;
    }

    // ---- lane-level inclusive scans (multiplier alpha^4) ----
    float a256;
    #pragma unroll
    for (int k = 0; k < 4; ++k) {
        float v = iv[k];
        float m = a4;
        #pragma unroll
        for (int off = 1; off < 64; off <<= 1) {
            float up = __shfl_up(v, off, 64);
            if (lane >= off) v = fmaf(m, up, v);
            m *= m;
        }
        iv[k] = v;
        a256 = m;                 // alpha^256
    }

    // ---- sub-block totals (broadcast lane 63) & wave total ----
    float T[4];
    T[0] = __shfl(iv[0], 63, 64);
    T[1] = __shfl(iv[1], 63, 64);
    T[2] = __shfl(iv[2], 63, 64);
    T[3] = __shfl(iv[3], 63, 64);
    const float Twave = fmaf(a256, fmaf(a256, fmaf(a256, T[0], T[1]), T[2]), T[3]);
    const float a1024 = (a256 * a256) * (a256 * a256);

    // ---- wave compose via LDS ----
    __shared__ float wtot[WAVES];
    if (lane == 0) wtot[wv] = Twave;
    __syncthreads();
    float P = 0.0f;                           // z entering this wave
    for (int w = 0; w < wv; ++w) P = fmaf(a1024, P, wtot[w]);

    // a4^lane via binary expansion
    float apl = 1.0f, b = a4;
    #pragma unroll
    for (int i = 0; i < 6; ++i) { if ((lane >> i) & 1) apl *= b; b *= b; }

    // ---- Phase C: replay y[i] = d[i] - beta*z[i-1]; mix; coalesced store ----
    float S  = 0.0f;                          // z entering sub-block k, zero wave entry
    float aK = 1.0f;                          // alpha^(256k)
    #pragma unroll
    for (int k = 0; k < 4; ++k) {
        const int j = wbase + k * 256 + lane * 4;
        const float Ck = fmaf(aK, P, S);              // z entering sub-block k
        float ex = __shfl_up(iv[k], 1, 64);           // z out of previous lane
        if (lane == 0) ex = 0.0f;
        const float zin = fmaf(apl, Ck, ex);          // z state before lane's run

        if (j >= outStart && j < N) {
            float4 xv;
            if (j + 4 <= N) {
                xv = *reinterpret_cast<const float4*>(xr + j);
            } else {
                xv.x = (j + 0 < N) ? xr[j + 0] : 0.0f;
                xv.y = (j + 1 < N) ? xr[j + 1] : 0.0f;
                xv.z = (j + 2 < N) ? xr[j + 2] : 0.0f;
                xv.w = (j + 3 < N) ? xr[j + 3] : 0.0f;
            }
            float z = zin;
            float4 ov;
            float y;
            y = fmaf(-beta, z, d4[k].x); ov.x = fmaf(om, xv.x, mm * y); z = fmaf(alpha, z, d4[k].x);
            y = fmaf(-beta, z, d4[k].y); ov.y = fmaf(om, xv.y, mm * y); z = fmaf(alpha, z, d4[k].y);
            y = fmaf(-beta, z, d4[k].z); ov.z = fmaf(om, xv.z, mm * y); z = fmaf(alpha, z, d4[k].z);
            y = fmaf(-beta, z, d4[k].w); ov.w = fmaf(om, xv.w, mm * y);
            if (j + 4 <= N) {
                *reinterpret_cast<float4*>(outr + j) = ov;
            } else {
                if (j + 0 < N) outr[j + 0] = ov.x;
                if (j + 1 < N) outr[j + 1] = ov.y;
                if (j + 2 < N) outr[j + 2] = ov.z;
                if (j + 3 < N) outr[j + 3] = ov.w;
            }
        }
        S  = fmaf(a256, S, T[k]);             // z entering sub-block k+1, zero wave entry
        aK *= a256;
    }
}

extern "C" void kernel_launch(void* const* d_in, const int* in_sizes, int n_in,
                              void* d_out, int out_size, void* d_ws, size_t ws_size,
                              hipStream_t stream) {
    const float* x     = (const float*)d_in[0];
    const float* drive = (const float*)d_in[1];
    const float* bias  = (const float*)d_in[2];
    const float* mixp  = (const float*)d_in[3];
    const int*   tyi   = (const int*)d_in[4];
    float* out = (float*)d_out;

    const int B = in_sizes[1];              // drive is (B,1)
    const int N = in_sizes[0] / B;

    const double alpha_d = exp(-2.0 * M_PI * 20.0 / 44100.0);
    const float alpha = (float)alpha_d;
    const float beta  = (float)(1.0 - alpha_d);

    const int nChunks = (N + CSZ - 1) / CSZ;
    dim3 grid(nChunks, B);
    dist_kernel<<<grid, TPB, 0, stream>>>(x, drive, bias, mixp, tyi, out, N, alpha, beta);
}

// Round 6
// 129.140 us; speedup vs baseline: 1.3052x; 1.0058x over previous
//
#include <hip/hip_runtime.h>
#include <math.h>

// Chunked parallel IIR, coalesced layout, z-formulation (no neighbor data).
//   z[i] = alpha*z[i-1] + d[i];  y[i] = d[i] - (1-alpha)*z[i-1]
// Each wave owns 1024 contiguous elements; access k is base+k*256+lane*4
// (contiguous 1KB per wave instruction). Each lane owns 4 runs of 4 elements.
// z composes: run summary (regs) -> lane scan (shfl, alpha^4) -> sub-block
// compose (alpha^256) -> wave compose via LDS (alpha^1024).
// Halo: a^2048 ~ 2.9e-3 error bound << 0.1075 threshold (measured 0.0156).
// R5/R6: single global read — mx = (1-mix)*x kept in regs, Phase C is pure
// register math + nontemporal stores (no post-barrier load stall).
#define TPB 1024
#define WAVES (TPB / 64)         // 16
#define PER_WAVE 1024
#define BLK (WAVES * PER_WAVE)   // 16384
#define HALO 2048
#define CSZ (BLK - HALO)         // 14336 output elements per block

typedef float v4f __attribute__((ext_vector_type(4)));

__device__ __forceinline__ float shape(float xs, int ty, float g, float dc,
                                       float c1, float c0) {
    if (ty == 0) {
        // tanh(p) = 1 - 2/(exp(2p)+1), exp folded: e2 = 2^(xs*c1 + c0)
        float e2 = __builtin_amdgcn_exp2f(fmaf(xs, c1, c0));
        return fmaf(-2.0f, __builtin_amdgcn_rcpf(e2 + 1.0f), 1.0f);
    }
    float p = (xs + dc) * g;
    if (ty == 1) {
        return fminf(fmaxf(p, -1.0f), 1.0f);
    } else if (ty == 2) {
        float r = p + 1.0f;
        float rem = r - 4.0f * floorf(r * 0.25f);   // jnp.remainder(r, 4)
        return fabsf(rem - 2.0f) - 1.0f;
    } else if (ty == 3) {
        return __sinf(p * 1.5707963267948966f);
    } else {
        return p / (1.0f + fabsf(p));
    }
}

__global__ void __launch_bounds__(TPB, 8)
dist_kernel(const float* __restrict__ x,
            const float* __restrict__ drive,
            const float* __restrict__ bias,
            const float* __restrict__ mix,
            const int* __restrict__ type_idx,
            float* __restrict__ out,
            int N, float alpha, float beta)
{
    const int row  = blockIdx.y;
    const int tid  = threadIdx.x;
    const int lane = tid & 63;
    const int wv   = tid >> 6;
    const int ty   = *type_idx;   // wave-uniform

    const float g  = exp2f(drive[row] * 7.972672880099267f);  // 10^(2.4*drive)
    const float dc = bias[row] * 2.0f - 1.0f;
    const float mm = mix[row];
    const float om = 1.0f - mm;
    // tanh fold: 2*log2(e) * g, 2*log2(e) * g * dc
    const float c1 = g * 2.8853900817779268f;
    const float c0 = dc * c1;

    const long long rowBase = (long long)row * (long long)N;
    const float* __restrict__ xr = x + rowBase;
    float* __restrict__ outr = out + rowBase;

    const int outStart = (int)blockIdx.x * CSZ;
    const int wbase = outStart - HALO + wv * PER_WAVE;

    // ---- Phase A: coalesced loads; keep d and mx = om*x in regs ----
    v4f d4[4];
    v4f mx4[4];
    #pragma unroll
    for (int k = 0; k < 4; ++k) {
        const int j = wbase + k * 256 + lane * 4;
        if (j >= 0 && j + 4 <= N) {
            v4f xv = *reinterpret_cast<const v4f*>(xr + j);
            mx4[k].x = om * xv.x; d4[k].x = shape(xv.x, ty, g, dc, c1, c0);
            mx4[k].y = om * xv.y; d4[k].y = shape(xv.y, ty, g, dc, c1, c0);
            mx4[k].z = om * xv.z; d4[k].z = shape(xv.z, ty, g, dc, c1, c0);
            mx4[k].w = om * xv.w; d4[k].w = shape(xv.w, ty, g, dc, c1, c0);
        } else {
            float xs; bool in;
            in = (j+0 >= 0) && (j+0 < N); xs = in ? xr[j+0] : 0.0f; mx4[k].x = om * xs; d4[k].x = in ? shape(xs, ty, g, dc, c1, c0) : 0.0f;
            in = (j+1 >= 0) && (j+1 < N); xs = in ? xr[j+1] : 0.0f; mx4[k].y = om * xs; d4[k].y = in ? shape(xs, ty, g, dc, c1, c0) : 0.0f;
            in = (j+2 >= 0) && (j+2 < N); xs = in ? xr[j+2] : 0.0f; mx4[k].z = om * xs; d4[k].z = in ? shape(xs, ty, g, dc, c1, c0) : 0.0f;
            in = (j+3 >= 0) && (j+3 < N); xs = in ? xr[j+3] : 0.0f; mx4[k].w = om * xs; d4[k].w = in ? shape(xs, ty, g, dc, c1, c0) : 0.0f;
        }
    }

    // ---- run summaries: z after lane's 4 elements, zero entry ----
    const float a2 = alpha * alpha;
    const float a4 = a2 * a2;
    float iv[4];
    #pragma unroll
    for (int k = 0; k < 4; ++k) {
        float acc = d4[k].x;
        acc = fmaf(alpha, acc, d4[k].y);
        acc = fmaf(alpha, acc, d4[k].z);
        acc = fmaf(alpha, acc, d4[k].w);
        iv[k] = acc;
    }

    // ---- lane-level inclusive scans (multiplier alpha^4) ----
    float a256;
    #pragma unroll
    for (int k = 0; k < 4; ++k) {
        float v = iv[k];
        float m = a4;
        #pragma unroll
        for (int off = 1; off < 64; off <<= 1) {
            float up = __shfl_up(v, off, 64);
            if (lane >= off) v = fmaf(m, up, v);
            m *= m;
        }
        iv[k] = v;
        a256 = m;                 // alpha^256
    }

    // ---- sub-block totals (broadcast lane 63) & wave total ----
    float T[4];
    T[0] = __shfl(iv[0], 63, 64);
    T[1] = __shfl(iv[1], 63, 64);
    T[2] = __shfl(iv[2], 63, 64);
    T[3] = __shfl(iv[3], 63, 64);
    const float Twave = fmaf(a256, fmaf(a256, fmaf(a256, T[0], T[1]), T[2]), T[3]);
    const float a1024 = (a256 * a256) * (a256 * a256);

    // ---- wave compose via LDS ----
    __shared__ float wtot[WAVES];
    if (lane == 0) wtot[wv] = Twave;
    __syncthreads();
    float P = 0.0f;                           // z entering this wave
    for (int w = 0; w < wv; ++w) P = fmaf(a1024, P, wtot[w]);

    // a4^lane via binary expansion
    float apl = 1.0f, b = a4;
    #pragma unroll
    for (int i = 0; i < 6; ++i) { if ((lane >> i) & 1) apl *= b; b *= b; }

    // ---- Phase C: y[i] = d[i] - beta*z[i-1]; out = mx + mm*y; pure regs ----
    float S  = 0.0f;                          // z entering sub-block k, zero wave entry
    float aK = 1.0f;                          // alpha^(256k)
    #pragma unroll
    for (int k = 0; k < 4; ++k) {
        const int j = wbase + k * 256 + lane * 4;
        const float Ck = fmaf(aK, P, S);              // z entering sub-block k
        float ex = __shfl_up(iv[k], 1, 64);           // z out of previous lane
        if (lane == 0) ex = 0.0f;
        const float zin = fmaf(apl, Ck, ex);          // z state before lane's run

        if (j >= outStart && j < N) {
            float z = zin;
            v4f ov;
            float y;
            y = fmaf(-beta, z, d4[k].x); ov.x = fmaf(mm, y, mx4[k].x); z = fmaf(alpha, z, d4[k].x);
            y = fmaf(-beta, z, d4[k].y); ov.y = fmaf(mm, y, mx4[k].y); z = fmaf(alpha, z, d4[k].y);
            y = fmaf(-beta, z, d4[k].z); ov.z = fmaf(mm, y, mx4[k].z); z = fmaf(alpha, z, d4[k].z);
            y = fmaf(-beta, z, d4[k].w); ov.w = fmaf(mm, y, mx4[k].w);
            if (j + 4 <= N) {
                __builtin_nontemporal_store(ov, reinterpret_cast<v4f*>(outr + j));
            } else {
                if (j + 0 < N) outr[j + 0] = ov.x;
                if (j + 1 < N) outr[j + 1] = ov.y;
                if (j + 2 < N) outr[j + 2] = ov.z;
                if (j + 3 < N) outr[j + 3] = ov.w;
            }
        }
        S  = fmaf(a256, S, T[k]);             // z entering sub-block k+1, zero wave entry
        aK *= a256;
    }
}

extern "C" void kernel_launch(void* const* d_in, const int* in_sizes, int n_in,
                              void* d_out, int out_size, void* d_ws, size_t ws_size,
                              hipStream_t stream) {
    const float* x     = (const float*)d_in[0];
    const float* drive = (const float*)d_in[1];
    const float* bias  = (const float*)d_in[2];
    const float* mixp  = (const float*)d_in[3];
    const int*   tyi   = (const int*)d_in[4];
    float* out = (float*)d_out;

    const int B = in_sizes[1];              // drive is (B,1)
    const int N = in_sizes[0] / B;

    const double alpha_d = exp(-2.0 * M_PI * 20.0 / 44100.0);
    const float alpha = (float)alpha_d;
    const float beta  = (float)(1.0 - alpha_d);

    const int nChunks = (N + CSZ - 1) / CSZ;
    dim3 grid(nChunks, B);
    dist_kernel<<<grid, TPB, 0, stream>>>(x, drive, bias, mixp, tyi, out, N, alpha, beta);
}